// Round 4
// baseline (348.841 us; speedup 1.0000x reference)
//
#include <hip/hip_runtime.h>
#include <hip/hip_bf16.h>

// Problem constants (B=8192, IN=H=1024)
#define BATCH 8192
#define HDIM  1024
#define KDIM  2048   // IN + H concatenated
#define NDIM  4096   // 4*H

__device__ inline unsigned short f2bf(float x) {
    unsigned int u = __float_as_uint(x);
    unsigned int r = (u + 0x7fffu + ((u >> 16) & 1u)) >> 16;
    return (unsigned short)r;
}
__device__ inline float bf2f(unsigned short u) {
    return __uint_as_float((unsigned int)u << 16);
}

typedef __attribute__((ext_vector_type(8))) unsigned short us8;

// Merged converter v2: 8 elems/thread, 16B stores (full-line coalescing).
//  Wb [4096,2048] bf16: row n = [w_i[n] | w_h[n]], w_i half zeroed for rows
//  2048..3071 (chunk i_gc of gi is unused by the reference).
//  Xb [8192,2048] bf16: row r = [input[r] | h_prev[r]]
__global__ __launch_bounds__(256) void convert_kernel(
    const float* __restrict__ wi, const float* __restrict__ wh,
    const float* __restrict__ input, const float* __restrict__ h_prev,
    unsigned short* __restrict__ Wb, unsigned short* __restrict__ Xb)
{
    int idx = blockIdx.x * 256 + threadIdx.x;
    const int NW = NDIM * 256;              // weight 8-elem groups per matrix
    float4 v0, v1;
    unsigned short* dst;
    if (idx < NW) {
        int n = idx >> 8;
        int k = (idx & 255) << 3;
        if (k < 1024) {
            if (n >= 2048 && n < 3072) {
                v0 = make_float4(0.f, 0.f, 0.f, 0.f);
                v1 = v0;
            } else {
                v0 = *(const float4*)(wi + (size_t)n * 1024 + k);
                v1 = *(const float4*)(wi + (size_t)n * 1024 + k + 4);
            }
        } else {
            v0 = *(const float4*)(wh + (size_t)n * 1024 + (k - 1024));
            v1 = *(const float4*)(wh + (size_t)n * 1024 + (k - 1024) + 4);
        }
        dst = Wb + (size_t)n * KDIM + k;
    } else {
        int j = idx - NW;
        int r = j >> 8;
        int k = (j & 255) << 3;
        if (k < 1024) {
            v0 = *(const float4*)(input + (size_t)r * 1024 + k);
            v1 = *(const float4*)(input + (size_t)r * 1024 + k + 4);
        } else {
            v0 = *(const float4*)(h_prev + (size_t)r * 1024 + (k - 1024));
            v1 = *(const float4*)(h_prev + (size_t)r * 1024 + (k - 1024) + 4);
        }
        dst = Xb + (size_t)r * KDIM + k;
    }
    us8 o;
    o[0] = f2bf(v0.x); o[1] = f2bf(v0.y); o[2] = f2bf(v0.z); o[3] = f2bf(v0.w);
    o[4] = f2bf(v1.x); o[5] = f2bf(v1.y); o[6] = f2bf(v1.z); o[7] = f2bf(v1.w);
    *(us8*)dst = o;
}

// ---------------------------------------------------------------------------
// GEMM (R4, verified 121us full-batch): G[M,N](bf16) = A * Bw^T
// 256x128 tile, 512 threads (8 waves, 4m x 2n of 64x64 wave-tiles), BK=64.
// XOR-swizzled LDS k-chunks -> 0 bank conflicts. 48KB LDS.
// R5 (256x256 dbuf) and R6 (3-deep ring) both lost occupancy and regressed;
// keep this 2-phase structure.
// R8: launched in 2 chunks of 4096 rows (512 blocks each) as a LOCALIZATION
// experiment -- drops the top-5 visibility threshold to ~65us and puts two
// gemm dispatches per iteration in the table so inter-gemm timestamp gaps
// directly measure the ew kernel + launch overhead.
// ---------------------------------------------------------------------------
#define BM 256
#define BN 128
#define BK 64    // bf16 elems per row; 128 B

typedef __attribute__((ext_vector_type(8))) short bf16x8;
typedef __attribute__((ext_vector_type(4))) float f32x4;

__global__ __launch_bounds__(512) void gemm_bt_kernel(
    const unsigned short* __restrict__ A,
    const unsigned short* __restrict__ Bw,
    unsigned short* __restrict__ G,
    int M)
{
    __shared__ unsigned short As[BM * BK];   // 32 KB
    __shared__ unsigned short Bs[BN * BK];   // 16 KB

    const int tid  = threadIdx.x;
    const int lane = tid & 63;
    const int wave = tid >> 6;               // 0..7

    const int bid = blockIdx.x;              // n-fastest linear
    const int bm  = (bid >> 5) * BM;
    const int bn  = (bid & 31) * BN;

    f32x4 acc[4][4] = {};

    const int wm = (wave >> 1) * 64;         // 0,64,128,192
    const int wn = (wave & 1) * 64;          // 0,64

    // staging: lane l covers row (l>>3) of its 8-row group, LDS chunk (l&7).
    // XOR swizzle: LDS row r, position p holds global k-chunk p ^ (r&7).
    const int srow = lane >> 3;              // 0..7
    const int c_sw = (lane & 7) ^ srow;      // global 16B-chunk to fetch

    int k0 = 0;
    if (bn >= 2048 && bn < 3072) k0 = 1024;  // w_i half of these rows is zero

    for (; k0 < KDIM; k0 += BK) {
        // A: 4 loads/wave covering rows [wave*32, wave*32+32)
#pragma unroll
        for (int p = 0; p < 4; ++p) {
            const int rbase = wave * 32 + p * 8;
            const unsigned short* gA =
                A + (size_t)(bm + rbase + srow) * KDIM + k0 + c_sw * 8;
            __builtin_amdgcn_global_load_lds(
                (const __attribute__((address_space(1))) void*)gA,
                (__attribute__((address_space(3))) void*)&As[rbase * BK], 16, 0, 0);
        }
        // B: 2 loads/wave covering rows [wave*16, wave*16+16)
#pragma unroll
        for (int p = 0; p < 2; ++p) {
            const int rbase = wave * 16 + p * 8;
            const unsigned short* gB =
                Bw + (size_t)(bn + rbase + srow) * KDIM + k0 + c_sw * 8;
            __builtin_amdgcn_global_load_lds(
                (const __attribute__((address_space(1))) void*)gB,
                (__attribute__((address_space(3))) void*)&Bs[rbase * BK], 16, 0, 0);
        }
        __syncthreads();

#pragma unroll
        for (int kk = 0; kk < 2; ++kk) {
            bf16x8 af[4], bfr[4];
            const int cbase = kk * 4 + (lane >> 4);   // 16B-chunk index 0..7
#pragma unroll
            for (int i = 0; i < 4; ++i) {
                const int ra = wm + i * 16 + (lane & 15);
                af[i]  = *(const bf16x8*)&As[ra * BK + ((cbase ^ (ra & 7)) * 8)];
                const int rb = wn + i * 16 + (lane & 15);
                bfr[i] = *(const bf16x8*)&Bs[rb * BK + ((cbase ^ (rb & 7)) * 8)];
            }
#pragma unroll
            for (int i = 0; i < 4; ++i)
#pragma unroll
                for (int j = 0; j < 4; ++j)
                    acc[i][j] = __builtin_amdgcn_mfma_f32_16x16x32_bf16(
                        af[i], bfr[j], acc[i][j], 0, 0, 0);
        }
        __syncthreads();
    }

    // Epilogue: C/D mapping col=lane&15, row=(lane>>4)*4+reg (m89-verified).
    // bf16 stores (2B): halves G write traffic.
#pragma unroll
    for (int i = 0; i < 4; ++i) {
#pragma unroll
        for (int j = 0; j < 4; ++j) {
#pragma unroll
            for (int r = 0; r < 4; ++r) {
                int row = bm + wm + i * 16 + (lane >> 4) * 4 + r;
                int col = bn + wn + j * 16 + (lane & 15);
                G[(size_t)row * NDIM + col] = f2bf(acc[i][j][r]);
            }
        }
    }
}

// ---------------------------------------------------------------------------
// Elementwise (v1 structure, restored): wave-per-row, pure shuffle
// reductions, no barriers / LDS. R7's 4-rows/wave + LDS-param variant cost
// ~+9us (TLP loss; param broadcast reads were already L2-served).
// G (bf16) row layout: [s0=i_i+h_i | s1=i_f+h_f | s2=h_g | s3=i_o+h_o]
// Lane l covers cols {j*512 + l*8 + e : j in 0..1, e in 0..7}.
// ---------------------------------------------------------------------------
__device__ inline float sigmoid_f(float x) { return 1.f / (1.f + __expf(-x)); }
// safe fast tanh: exact +/-1 saturation at both ends
__device__ inline float tanh_f(float x) { return 1.f - 2.f / (__expf(2.f * x) + 1.f); }

__device__ inline void wstats(const float* x, float& mu, float& rs)
{
    float s = 0.f, q = 0.f;
#pragma unroll
    for (int e = 0; e < 16; ++e) { s += x[e]; q += x[e] * x[e]; }
#pragma unroll
    for (int o = 1; o < 64; o <<= 1) {
        s += __shfl_xor(s, o);
        q += __shfl_xor(q, o);
    }
    mu = s * (1.f / 1024.f);
    float var = q * (1.f / 1024.f) - mu * mu;
    rs = rsqrtf(var + 1e-5f);
}

// 16 bf16 -> fp32 per thread: two 16B ushort8 loads
#define LOADG16(dst, basep)                                            \
    _Pragma("unroll")                                                  \
    for (int j = 0; j < 2; ++j) {                                      \
        us8 t = *(const us8*)((basep) + j * 512 + cbase);              \
        _Pragma("unroll")                                              \
        for (int e = 0; e < 8; ++e) dst[j * 8 + e] = bf2f(t[e]);       \
    }

// 16 fp32 per thread (params / c_prev): four float4 loads
#define LOADF16(dst, basep)                                            \
    _Pragma("unroll")                                                  \
    for (int j = 0; j < 2; ++j) {                                      \
        float4 a = *(const float4*)((basep) + j * 512 + cbase);        \
        float4 b = *(const float4*)((basep) + j * 512 + cbase + 4);    \
        dst[j * 8 + 0] = a.x; dst[j * 8 + 1] = a.y;                    \
        dst[j * 8 + 2] = a.z; dst[j * 8 + 3] = a.w;                    \
        dst[j * 8 + 4] = b.x; dst[j * 8 + 5] = b.y;                    \
        dst[j * 8 + 6] = b.z; dst[j * 8 + 7] = b.w;                    \
    }

__global__ __launch_bounds__(256) void lstm_ew_kernel(
    const unsigned short* __restrict__ G,
    const float* __restrict__ c_prev,
    const float* __restrict__ p0g, const float* __restrict__ p0b,
    const float* __restrict__ p1g, const float* __restrict__ p1b,
    const float* __restrict__ p2g, const float* __restrict__ p2b,
    const float* __restrict__ p3g, const float* __restrict__ p3b,
    const float* __restrict__ p4g, const float* __restrict__ p4b,
    float* __restrict__ out_h, float* __restrict__ out_c,
    int row_base)
{
    const int lane  = threadIdx.x & 63;
    const int wave  = threadIdx.x >> 6;
    const int r     = blockIdx.x * 4 + wave;
    const int grow  = row_base + r;
    const int cbase = lane * 8;

    const unsigned short* Grow = G + (size_t)r * NDIM;

    float tmp[16], pg[16], pb[16];
    float ig[16], cm[16], og[16];
    float mu, rs;

    // i gate: sigmoid(LN(i_i+h_i; ln_i))
    LOADG16(tmp, Grow);
    wstats(tmp, mu, rs);
    LOADF16(pg, p0g); LOADF16(pb, p0b);
#pragma unroll
    for (int e = 0; e < 16; ++e)
        ig[e] = sigmoid_f((tmp[e] - mu) * rs * pg[e] + pb[e]);

    // f gate: sigmoid(LN(i_f+h_f; ln_h)); cm = f * c_prev
    LOADG16(tmp, Grow + 1024);
    wstats(tmp, mu, rs);
    LOADF16(pg, p1g); LOADF16(pb, p1b);
    LOADF16(cm, c_prev + (size_t)grow * HDIM);
#pragma unroll
    for (int e = 0; e < 16; ++e)
        cm[e] *= sigmoid_f((tmp[e] - mu) * rs * pg[e] + pb[e]);

    // g gate: tanh(LN(i_g + h_g; ln_g))  <- faithful bug: i_g is sigmoided gate
    LOADG16(tmp, Grow + 2048);
#pragma unroll
    for (int e = 0; e < 16; ++e) tmp[e] += ig[e];
    wstats(tmp, mu, rs);
    LOADF16(pg, p2g); LOADF16(pb, p2b);
#pragma unroll
    for (int e = 0; e < 16; ++e)
        cm[e] += ig[e] * tanh_f((tmp[e] - mu) * rs * pg[e] + pb[e]);

    // o gate: sigmoid(LN(i_o+h_o; ln_o))
    LOADG16(tmp, Grow + 3072);
    wstats(tmp, mu, rs);
    LOADF16(pg, p3g); LOADF16(pb, p3b);
#pragma unroll
    for (int e = 0; e < 16; ++e)
        og[e] = sigmoid_f((tmp[e] - mu) * rs * pg[e] + pb[e]);

    // c_new = LN(cm; ln_c); h_new = o * tanh(c_new)
    wstats(cm, mu, rs);
    LOADF16(pg, p4g); LOADF16(pb, p4b);
    float cn[16], hn[16];
#pragma unroll
    for (int e = 0; e < 16; ++e) {
        cn[e] = (cm[e] - mu) * rs * pg[e] + pb[e];
        hn[e] = og[e] * tanh_f(cn[e]);
    }

    float* oh = out_h + (size_t)grow * HDIM;
    float* oc = out_c + (size_t)grow * HDIM;
#pragma unroll
    for (int j = 0; j < 2; ++j) {
        *(float4*)(oh + j * 512 + cbase) =
            make_float4(hn[j*8+0], hn[j*8+1], hn[j*8+2], hn[j*8+3]);
        *(float4*)(oh + j * 512 + cbase + 4) =
            make_float4(hn[j*8+4], hn[j*8+5], hn[j*8+6], hn[j*8+7]);
        *(float4*)(oc + j * 512 + cbase) =
            make_float4(cn[j*8+0], cn[j*8+1], cn[j*8+2], cn[j*8+3]);
        *(float4*)(oc + j * 512 + cbase + 4) =
            make_float4(cn[j*8+4], cn[j*8+5], cn[j*8+6], cn[j*8+7]);
    }
}

extern "C" void kernel_launch(void* const* d_in, const int* in_sizes, int n_in,
                              void* d_out, int out_size, void* d_ws, size_t ws_size,
                              hipStream_t stream)
{
    const float* input  = (const float*)d_in[0];
    const float* h_prev = (const float*)d_in[1];
    const float* c_prev = (const float*)d_in[2];
    const float* w_i    = (const float*)d_in[3];
    const float* w_h    = (const float*)d_in[4];
    const float* lng[10];
    for (int i = 0; i < 10; ++i) lng[i] = (const float*)d_in[5 + i];

    // Workspace: Xb bf16 [8192,2048] | Wb bf16 [4096,2048] | G bf16 [chunk,4096]
    unsigned short* Xb = (unsigned short*)d_ws;
    size_t xb_bytes = (size_t)BATCH * KDIM * 2;
    unsigned short* Wb = (unsigned short*)((char*)d_ws + xb_bytes);
    size_t wb_bytes = (size_t)NDIM * KDIM * 2;
    unsigned short* G = (unsigned short*)((char*)d_ws + xb_bytes + wb_bytes);

    size_t g_avail = (ws_size > xb_bytes + wb_bytes) ? (ws_size - xb_bytes - wb_bytes) : 0;
    long max_rows = (long)(g_avail / ((size_t)NDIM * sizeof(unsigned short)));
    // R8 localization: force 2 chunks of 4096 (gemm 512 blocks each) so two
    // gemm dispatches land in the top-5 per iteration; their timestamp gap
    // measures ew + launch overhead directly.
    int chunk = 4096;
    if (max_rows < chunk) chunk = (int)((max_rows / BM) * BM);
    if (chunk <= 0) chunk = BM;   // last-resort assumption

    convert_kernel<<<(NDIM * 256 + BATCH * 256) / 256, 256, 0, stream>>>(
        w_i, w_h, input, h_prev, Wb, Xb);

    float* out_h = (float*)d_out;
    float* out_c = out_h + (size_t)BATCH * HDIM;

    for (int rb = 0; rb < BATCH; rb += chunk) {
        int rows = (BATCH - rb < chunk) ? (BATCH - rb) : chunk;
        gemm_bt_kernel<<<(rows / BM) * (NDIM / BN), 512, 0, stream>>>(
            Xb + (size_t)rb * KDIM, Wb, G, rows);
        lstm_ew_kernel<<<rows / 4, 256, 0, stream>>>(
            G, c_prev, lng[0], lng[1], lng[2], lng[3], lng[4],
            lng[5], lng[6], lng[7], lng[8], lng[9], out_h, out_c, rb);
    }
}

// Round 5
// 341.312 us; speedup vs baseline: 1.0221x; 1.0221x over previous
//
#include <hip/hip_runtime.h>
#include <hip/hip_bf16.h>

// Problem constants (B=8192, IN=H=1024)
#define BATCH 8192
#define HDIM  1024
#define KDIM  2048   // IN + H concatenated
#define NDIM  4096   // 4*H

__device__ inline unsigned short f2bf(float x) {
    unsigned int u = __float_as_uint(x);
    unsigned int r = (u + 0x7fffu + ((u >> 16) & 1u)) >> 16;
    return (unsigned short)r;
}
__device__ inline float bf2f(unsigned short u) {
    return __uint_as_float((unsigned int)u << 16);
}

typedef __attribute__((ext_vector_type(8))) unsigned short us8;

// Merged converter v2: 8 elems/thread, 16B stores (full-line coalescing).
//  Wb [4096,2048] bf16: row n = [w_i[n] | w_h[n]], w_i half zeroed for rows
//  2048..3071 (chunk i_gc of gi is unused by the reference).
//  Xb [8192,2048] bf16: row r = [input[r] | h_prev[r]]
// R8 localization: convert never appeared above the ~61us top-5 threshold
// -> convert <= ~61us.
__global__ __launch_bounds__(256) void convert_kernel(
    const float* __restrict__ wi, const float* __restrict__ wh,
    const float* __restrict__ input, const float* __restrict__ h_prev,
    unsigned short* __restrict__ Wb, unsigned short* __restrict__ Xb)
{
    int idx = blockIdx.x * 256 + threadIdx.x;
    const int NW = NDIM * 256;              // weight 8-elem groups per matrix
    float4 v0, v1;
    unsigned short* dst;
    if (idx < NW) {
        int n = idx >> 8;
        int k = (idx & 255) << 3;
        if (k < 1024) {
            if (n >= 2048 && n < 3072) {
                v0 = make_float4(0.f, 0.f, 0.f, 0.f);
                v1 = v0;
            } else {
                v0 = *(const float4*)(wi + (size_t)n * 1024 + k);
                v1 = *(const float4*)(wi + (size_t)n * 1024 + k + 4);
            }
        } else {
            v0 = *(const float4*)(wh + (size_t)n * 1024 + (k - 1024));
            v1 = *(const float4*)(wh + (size_t)n * 1024 + (k - 1024) + 4);
        }
        dst = Wb + (size_t)n * KDIM + k;
    } else {
        int j = idx - NW;
        int r = j >> 8;
        int k = (j & 255) << 3;
        if (k < 1024) {
            v0 = *(const float4*)(input + (size_t)r * 1024 + k);
            v1 = *(const float4*)(input + (size_t)r * 1024 + k + 4);
        } else {
            v0 = *(const float4*)(h_prev + (size_t)r * 1024 + (k - 1024));
            v1 = *(const float4*)(h_prev + (size_t)r * 1024 + (k - 1024) + 4);
        }
        dst = Xb + (size_t)r * KDIM + k;
    }
    us8 o;
    o[0] = f2bf(v0.x); o[1] = f2bf(v0.y); o[2] = f2bf(v0.z); o[3] = f2bf(v0.w);
    o[4] = f2bf(v1.x); o[5] = f2bf(v1.y); o[6] = f2bf(v1.z); o[7] = f2bf(v1.w);
    *(us8*)dst = o;
}

// ---------------------------------------------------------------------------
// GEMM (R4, verified): G[M,N](bf16) = A * Bw^T
// 256x128 tile, 512 threads (8 waves, 4m x 2n of 64x64 wave-tiles), BK=64.
// XOR-swizzled LDS k-chunks -> 0 bank conflicts. 48KB LDS.
// R5 (256x256 dbuf) and R6 (3-deep ring) both lost occupancy and regressed;
// keep this 2-phase structure. R8: 2 chunks of 4096 scale cleanly
// (2x61.2us ~ 121us full-batch).
// ---------------------------------------------------------------------------
#define BM 256
#define BN 128
#define BK 64    // bf16 elems per row; 128 B

typedef __attribute__((ext_vector_type(8))) short bf16x8;
typedef __attribute__((ext_vector_type(4))) float f32x4;

__global__ __launch_bounds__(512) void gemm_bt_kernel(
    const unsigned short* __restrict__ A,
    const unsigned short* __restrict__ Bw,
    unsigned short* __restrict__ G,
    int M)
{
    __shared__ unsigned short As[BM * BK];   // 32 KB
    __shared__ unsigned short Bs[BN * BK];   // 16 KB

    const int tid  = threadIdx.x;
    const int lane = tid & 63;
    const int wave = tid >> 6;               // 0..7

    const int bid = blockIdx.x;              // n-fastest linear
    const int bm  = (bid >> 5) * BM;
    const int bn  = (bid & 31) * BN;

    f32x4 acc[4][4] = {};

    const int wm = (wave >> 1) * 64;         // 0,64,128,192
    const int wn = (wave & 1) * 64;          // 0,64

    // staging: lane l covers row (l>>3) of its 8-row group, LDS chunk (l&7).
    // XOR swizzle: LDS row r, position p holds global k-chunk p ^ (r&7).
    const int srow = lane >> 3;              // 0..7
    const int c_sw = (lane & 7) ^ srow;      // global 16B-chunk to fetch

    int k0 = 0;
    if (bn >= 2048 && bn < 3072) k0 = 1024;  // w_i half of these rows is zero

    for (; k0 < KDIM; k0 += BK) {
        // A: 4 loads/wave covering rows [wave*32, wave*32+32)
#pragma unroll
        for (int p = 0; p < 4; ++p) {
            const int rbase = wave * 32 + p * 8;
            const unsigned short* gA =
                A + (size_t)(bm + rbase + srow) * KDIM + k0 + c_sw * 8;
            __builtin_amdgcn_global_load_lds(
                (const __attribute__((address_space(1))) void*)gA,
                (__attribute__((address_space(3))) void*)&As[rbase * BK], 16, 0, 0);
        }
        // B: 2 loads/wave covering rows [wave*16, wave*16+16)
#pragma unroll
        for (int p = 0; p < 2; ++p) {
            const int rbase = wave * 16 + p * 8;
            const unsigned short* gB =
                Bw + (size_t)(bn + rbase + srow) * KDIM + k0 + c_sw * 8;
            __builtin_amdgcn_global_load_lds(
                (const __attribute__((address_space(1))) void*)gB,
                (__attribute__((address_space(3))) void*)&Bs[rbase * BK], 16, 0, 0);
        }
        __syncthreads();

#pragma unroll
        for (int kk = 0; kk < 2; ++kk) {
            bf16x8 af[4], bfr[4];
            const int cbase = kk * 4 + (lane >> 4);   // 16B-chunk index 0..7
#pragma unroll
            for (int i = 0; i < 4; ++i) {
                const int ra = wm + i * 16 + (lane & 15);
                af[i]  = *(const bf16x8*)&As[ra * BK + ((cbase ^ (ra & 7)) * 8)];
                const int rb = wn + i * 16 + (lane & 15);
                bfr[i] = *(const bf16x8*)&Bs[rb * BK + ((cbase ^ (rb & 7)) * 8)];
            }
#pragma unroll
            for (int i = 0; i < 4; ++i)
#pragma unroll
                for (int j = 0; j < 4; ++j)
                    acc[i][j] = __builtin_amdgcn_mfma_f32_16x16x32_bf16(
                        af[i], bfr[j], acc[i][j], 0, 0, 0);
        }
        __syncthreads();
    }

    // Epilogue: C/D mapping col=lane&15, row=(lane>>4)*4+reg (m89-verified).
    // bf16 stores (2B): halves G write traffic.
#pragma unroll
    for (int i = 0; i < 4; ++i) {
#pragma unroll
        for (int j = 0; j < 4; ++j) {
#pragma unroll
            for (int r = 0; r < 4; ++r) {
                int row = bm + wm + i * 16 + (lane >> 4) * 4 + r;
                int col = bn + wn + j * 16 + (lane & 15);
                G[(size_t)row * NDIM + col] = f2bf(acc[i][j][r]);
            }
        }
    }
}

// ---------------------------------------------------------------------------
// Elementwise (v1, verified): wave-per-row, pure shuffle reductions.
// R9: launched ONCE over the full 8192 rows AFTER both gemm chunks, so its
// duration (2x an R8 ew-chunk) must exceed the ~61us gemm threshold if ew is
// the hidden cost -> it floods the top-5 and we read duration + counters.
// If the top-5 stays gemm@61, ew_full <= ~63 and launch gaps >= ~100us.
// G (bf16) row layout: [s0=i_i+h_i | s1=i_f+h_f | s2=h_g | s3=i_o+h_o]
// Lane l covers cols {j*512 + l*8 + e : j in 0..1, e in 0..7}.
// ---------------------------------------------------------------------------
__device__ inline float sigmoid_f(float x) { return 1.f / (1.f + __expf(-x)); }
// safe fast tanh: exact +/-1 saturation at both ends
__device__ inline float tanh_f(float x) { return 1.f - 2.f / (__expf(2.f * x) + 1.f); }

__device__ inline void wstats(const float* x, float& mu, float& rs)
{
    float s = 0.f, q = 0.f;
#pragma unroll
    for (int e = 0; e < 16; ++e) { s += x[e]; q += x[e] * x[e]; }
#pragma unroll
    for (int o = 1; o < 64; o <<= 1) {
        s += __shfl_xor(s, o);
        q += __shfl_xor(q, o);
    }
    mu = s * (1.f / 1024.f);
    float var = q * (1.f / 1024.f) - mu * mu;
    rs = rsqrtf(var + 1e-5f);
}

// 16 bf16 -> fp32 per thread: two 16B ushort8 loads
#define LOADG16(dst, basep)                                            \
    _Pragma("unroll")                                                  \
    for (int j = 0; j < 2; ++j) {                                      \
        us8 t = *(const us8*)((basep) + j * 512 + cbase);              \
        _Pragma("unroll")                                              \
        for (int e = 0; e < 8; ++e) dst[j * 8 + e] = bf2f(t[e]);       \
    }

// 16 fp32 per thread (params / c_prev): four float4 loads
#define LOADF16(dst, basep)                                            \
    _Pragma("unroll")                                                  \
    for (int j = 0; j < 2; ++j) {                                      \
        float4 a = *(const float4*)((basep) + j * 512 + cbase);        \
        float4 b = *(const float4*)((basep) + j * 512 + cbase + 4);    \
        dst[j * 8 + 0] = a.x; dst[j * 8 + 1] = a.y;                    \
        dst[j * 8 + 2] = a.z; dst[j * 8 + 3] = a.w;                    \
        dst[j * 8 + 4] = b.x; dst[j * 8 + 5] = b.y;                    \
        dst[j * 8 + 6] = b.z; dst[j * 8 + 7] = b.w;                    \
    }

__global__ __launch_bounds__(256) void lstm_ew_kernel(
    const unsigned short* __restrict__ G,
    const float* __restrict__ c_prev,
    const float* __restrict__ p0g, const float* __restrict__ p0b,
    const float* __restrict__ p1g, const float* __restrict__ p1b,
    const float* __restrict__ p2g, const float* __restrict__ p2b,
    const float* __restrict__ p3g, const float* __restrict__ p3b,
    const float* __restrict__ p4g, const float* __restrict__ p4b,
    float* __restrict__ out_h, float* __restrict__ out_c,
    int row_base)
{
    const int lane  = threadIdx.x & 63;
    const int wave  = threadIdx.x >> 6;
    const int r     = blockIdx.x * 4 + wave;
    const int grow  = row_base + r;
    const int cbase = lane * 8;

    const unsigned short* Grow = G + (size_t)r * NDIM;

    float tmp[16], pg[16], pb[16];
    float ig[16], cm[16], og[16];
    float mu, rs;

    // i gate: sigmoid(LN(i_i+h_i; ln_i))
    LOADG16(tmp, Grow);
    wstats(tmp, mu, rs);
    LOADF16(pg, p0g); LOADF16(pb, p0b);
#pragma unroll
    for (int e = 0; e < 16; ++e)
        ig[e] = sigmoid_f((tmp[e] - mu) * rs * pg[e] + pb[e]);

    // f gate: sigmoid(LN(i_f+h_f; ln_h)); cm = f * c_prev
    LOADG16(tmp, Grow + 1024);
    wstats(tmp, mu, rs);
    LOADF16(pg, p1g); LOADF16(pb, p1b);
    LOADF16(cm, c_prev + (size_t)grow * HDIM);
#pragma unroll
    for (int e = 0; e < 16; ++e)
        cm[e] *= sigmoid_f((tmp[e] - mu) * rs * pg[e] + pb[e]);

    // g gate: tanh(LN(i_g + h_g; ln_g))  <- faithful bug: i_g is sigmoided gate
    LOADG16(tmp, Grow + 2048);
#pragma unroll
    for (int e = 0; e < 16; ++e) tmp[e] += ig[e];
    wstats(tmp, mu, rs);
    LOADF16(pg, p2g); LOADF16(pb, p2b);
#pragma unroll
    for (int e = 0; e < 16; ++e)
        cm[e] += ig[e] * tanh_f((tmp[e] - mu) * rs * pg[e] + pb[e]);

    // o gate: sigmoid(LN(i_o+h_o; ln_o))
    LOADG16(tmp, Grow + 3072);
    wstats(tmp, mu, rs);
    LOADF16(pg, p3g); LOADF16(pb, p3b);
#pragma unroll
    for (int e = 0; e < 16; ++e)
        og[e] = sigmoid_f((tmp[e] - mu) * rs * pg[e] + pb[e]);

    // c_new = LN(cm; ln_c); h_new = o * tanh(c_new)
    wstats(cm, mu, rs);
    LOADF16(pg, p4g); LOADF16(pb, p4b);
    float cn[16], hn[16];
#pragma unroll
    for (int e = 0; e < 16; ++e) {
        cn[e] = (cm[e] - mu) * rs * pg[e] + pb[e];
        hn[e] = og[e] * tanh_f(cn[e]);
    }

    float* oh = out_h + (size_t)grow * HDIM;
    float* oc = out_c + (size_t)grow * HDIM;
#pragma unroll
    for (int j = 0; j < 2; ++j) {
        *(float4*)(oh + j * 512 + cbase) =
            make_float4(hn[j*8+0], hn[j*8+1], hn[j*8+2], hn[j*8+3]);
        *(float4*)(oh + j * 512 + cbase + 4) =
            make_float4(hn[j*8+4], hn[j*8+5], hn[j*8+6], hn[j*8+7]);
        *(float4*)(oc + j * 512 + cbase) =
            make_float4(cn[j*8+0], cn[j*8+1], cn[j*8+2], cn[j*8+3]);
        *(float4*)(oc + j * 512 + cbase + 4) =
            make_float4(cn[j*8+4], cn[j*8+5], cn[j*8+6], cn[j*8+7]);
    }
}

extern "C" void kernel_launch(void* const* d_in, const int* in_sizes, int n_in,
                              void* d_out, int out_size, void* d_ws, size_t ws_size,
                              hipStream_t stream)
{
    const float* input  = (const float*)d_in[0];
    const float* h_prev = (const float*)d_in[1];
    const float* c_prev = (const float*)d_in[2];
    const float* w_i    = (const float*)d_in[3];
    const float* w_h    = (const float*)d_in[4];
    const float* lng[10];
    for (int i = 0; i < 10; ++i) lng[i] = (const float*)d_in[5 + i];

    // Workspace: Xb bf16 [8192,2048] | Wb bf16 [4096,2048] | G bf16 [8192,4096]
    // (117.4 MB total; full-batch G proven to fit in R0-R4.)
    unsigned short* Xb = (unsigned short*)d_ws;
    size_t xb_bytes = (size_t)BATCH * KDIM * 2;
    unsigned short* Wb = (unsigned short*)((char*)d_ws + xb_bytes);
    size_t wb_bytes = (size_t)NDIM * KDIM * 2;
    unsigned short* G = (unsigned short*)((char*)d_ws + xb_bytes + wb_bytes);

    convert_kernel<<<(NDIM * 256 + BATCH * 256) / 256, 256, 0, stream>>>(
        w_i, w_h, input, h_prev, Wb, Xb);

    float* out_h = (float*)d_out;
    float* out_c = out_h + (size_t)BATCH * HDIM;

    // R9 localization: gemm in 2 chunks (threshold ~61us), ew as ONE
    // full-batch launch (must flood top-5 if it's the hidden cost).
    const int chunk = 4096;
    for (int rb = 0; rb < BATCH; rb += chunk) {
        gemm_bt_kernel<<<(chunk / BM) * (NDIM / BN), 512, 0, stream>>>(
            Xb + (size_t)rb * KDIM, Wb, G + (size_t)rb * NDIM, chunk);
    }
    lstm_ew_kernel<<<BATCH / 4, 256, 0, stream>>>(
        G, c_prev, lng[0], lng[1], lng[2], lng[3], lng[4],
        lng[5], lng[6], lng[7], lng[8], lng[9], out_h, out_c, 0);
}

// Round 6
// 330.596 us; speedup vs baseline: 1.0552x; 1.0324x over previous
//
#include <hip/hip_runtime.h>
#include <hip/hip_bf16.h>

// Problem constants (B=8192, IN=H=1024)
#define BATCH 8192
#define HDIM  1024
#define KDIM  2048   // IN + H concatenated
#define NDIM  4096   // 4*H

__device__ inline unsigned short f2bf(float x) {
    unsigned int u = __float_as_uint(x);
    unsigned int r = (u + 0x7fffu + ((u >> 16) & 1u)) >> 16;
    return (unsigned short)r;
}
__device__ inline float bf2f(unsigned short u) {
    return __uint_as_float((unsigned int)u << 16);
}

typedef __attribute__((ext_vector_type(8))) unsigned short us8;

// Merged converter v2: 8 elems/thread, 16B stores (full-line coalescing).
//  Wb [4096,2048] bf16: row n = [w_i[n] | w_h[n]], w_i half zeroed for rows
//  2048..3071 (chunk i_gc of gi is unused by the reference).
//  Xb [8192,2048] bf16: row r = [input[r] | h_prev[r]]
// R8/R9 localization: convert never appeared above the ~61us top-5
// threshold -> convert <= ~61us.
__global__ __launch_bounds__(256) void convert_kernel(
    const float* __restrict__ wi, const float* __restrict__ wh,
    const float* __restrict__ input, const float* __restrict__ h_prev,
    unsigned short* __restrict__ Wb, unsigned short* __restrict__ Xb)
{
    int idx = blockIdx.x * 256 + threadIdx.x;
    const int NW = NDIM * 256;              // weight 8-elem groups per matrix
    float4 v0, v1;
    unsigned short* dst;
    if (idx < NW) {
        int n = idx >> 8;
        int k = (idx & 255) << 3;
        if (k < 1024) {
            if (n >= 2048 && n < 3072) {
                v0 = make_float4(0.f, 0.f, 0.f, 0.f);
                v1 = v0;
            } else {
                v0 = *(const float4*)(wi + (size_t)n * 1024 + k);
                v1 = *(const float4*)(wi + (size_t)n * 1024 + k + 4);
            }
        } else {
            v0 = *(const float4*)(wh + (size_t)n * 1024 + (k - 1024));
            v1 = *(const float4*)(wh + (size_t)n * 1024 + (k - 1024) + 4);
        }
        dst = Wb + (size_t)n * KDIM + k;
    } else {
        int j = idx - NW;
        int r = j >> 8;
        int k = (j & 255) << 3;
        if (k < 1024) {
            v0 = *(const float4*)(input + (size_t)r * 1024 + k);
            v1 = *(const float4*)(input + (size_t)r * 1024 + k + 4);
        } else {
            v0 = *(const float4*)(h_prev + (size_t)r * 1024 + (k - 1024));
            v1 = *(const float4*)(h_prev + (size_t)r * 1024 + (k - 1024) + 4);
        }
        dst = Xb + (size_t)r * KDIM + k;
    }
    us8 o;
    o[0] = f2bf(v0.x); o[1] = f2bf(v0.y); o[2] = f2bf(v0.z); o[3] = f2bf(v0.w);
    o[4] = f2bf(v1.x); o[5] = f2bf(v1.y); o[6] = f2bf(v1.z); o[7] = f2bf(v1.w);
    *(us8*)dst = o;
}

// ---------------------------------------------------------------------------
// GEMM (R4, verified 121us full-batch): G[M,N](bf16) = A * Bw^T
// 256x128 tile, 512 threads (8 waves, 4m x 2n of 64x64 wave-tiles), BK=64.
// XOR-swizzled LDS k-chunks -> 0 bank conflicts. 48KB LDS -> 3 blocks/CU:
// inter-block wave overlap (m114) is what hides the barrier drain.
// R5 (256x256 dbuf) and R6 (3-deep ring) both lost occupancy and regressed;
// keep this 2-phase structure. R8/R9: chunked launches scale cleanly but
// cost ~8-9us per extra launch -> single full-batch launch.
// ---------------------------------------------------------------------------
#define BM 256
#define BN 128
#define BK 64    // bf16 elems per row; 128 B

typedef __attribute__((ext_vector_type(8))) short bf16x8;
typedef __attribute__((ext_vector_type(4))) float f32x4;

__global__ __launch_bounds__(512) void gemm_bt_kernel(
    const unsigned short* __restrict__ A,
    const unsigned short* __restrict__ Bw,
    unsigned short* __restrict__ G,
    int M)
{
    __shared__ unsigned short As[BM * BK];   // 32 KB
    __shared__ unsigned short Bs[BN * BK];   // 16 KB

    const int tid  = threadIdx.x;
    const int lane = tid & 63;
    const int wave = tid >> 6;               // 0..7

    const int bid = blockIdx.x;              // n-fastest linear
    const int bm  = (bid >> 5) * BM;
    const int bn  = (bid & 31) * BN;

    f32x4 acc[4][4] = {};

    const int wm = (wave >> 1) * 64;         // 0,64,128,192
    const int wn = (wave & 1) * 64;          // 0,64

    // staging: lane l covers row (l>>3) of its 8-row group, LDS chunk (l&7).
    // XOR swizzle: LDS row r, position p holds global k-chunk p ^ (r&7).
    const int srow = lane >> 3;              // 0..7
    const int c_sw = (lane & 7) ^ srow;      // global 16B-chunk to fetch

    int k0 = 0;
    if (bn >= 2048 && bn < 3072) k0 = 1024;  // w_i half of these rows is zero

    for (; k0 < KDIM; k0 += BK) {
        // A: 4 loads/wave covering rows [wave*32, wave*32+32)
#pragma unroll
        for (int p = 0; p < 4; ++p) {
            const int rbase = wave * 32 + p * 8;
            const unsigned short* gA =
                A + (size_t)(bm + rbase + srow) * KDIM + k0 + c_sw * 8;
            __builtin_amdgcn_global_load_lds(
                (const __attribute__((address_space(1))) void*)gA,
                (__attribute__((address_space(3))) void*)&As[rbase * BK], 16, 0, 0);
        }
        // B: 2 loads/wave covering rows [wave*16, wave*16+16)
#pragma unroll
        for (int p = 0; p < 2; ++p) {
            const int rbase = wave * 16 + p * 8;
            const unsigned short* gB =
                Bw + (size_t)(bn + rbase + srow) * KDIM + k0 + c_sw * 8;
            __builtin_amdgcn_global_load_lds(
                (const __attribute__((address_space(1))) void*)gB,
                (__attribute__((address_space(3))) void*)&Bs[rbase * BK], 16, 0, 0);
        }
        __syncthreads();

#pragma unroll
        for (int kk = 0; kk < 2; ++kk) {
            bf16x8 af[4], bfr[4];
            const int cbase = kk * 4 + (lane >> 4);   // 16B-chunk index 0..7
#pragma unroll
            for (int i = 0; i < 4; ++i) {
                const int ra = wm + i * 16 + (lane & 15);
                af[i]  = *(const bf16x8*)&As[ra * BK + ((cbase ^ (ra & 7)) * 8)];
                const int rb = wn + i * 16 + (lane & 15);
                bfr[i] = *(const bf16x8*)&Bs[rb * BK + ((cbase ^ (rb & 7)) * 8)];
            }
#pragma unroll
            for (int i = 0; i < 4; ++i)
#pragma unroll
                for (int j = 0; j < 4; ++j)
                    acc[i][j] = __builtin_amdgcn_mfma_f32_16x16x32_bf16(
                        af[i], bfr[j], acc[i][j], 0, 0, 0);
        }
        __syncthreads();
    }

    // Epilogue: C/D mapping col=lane&15, row=(lane>>4)*4+reg (m89-verified).
    // bf16 stores (2B): halves G write traffic.
#pragma unroll
    for (int i = 0; i < 4; ++i) {
#pragma unroll
        for (int j = 0; j < 4; ++j) {
#pragma unroll
            for (int r = 0; r < 4; ++r) {
                int row = bm + wm + i * 16 + (lane >> 4) * 4 + r;
                int col = bn + wn + j * 16 + (lane & 15);
                G[(size_t)row * NDIM + col] = f2bf(acc[i][j][r]);
            }
        }
    }
}

// ---------------------------------------------------------------------------
// Elementwise (R10): wave-per-row, pure shuffle reductions, no barriers/LDS.
// R10 fix: harness compiles WITHOUT -ffast-math, so `1.f/(1.f+e)` lowered to
// the full IEEE divide sequence (v_div_scale + v_rcp + v_div_fmas +
// v_div_fixup, ~7-10 instr, 2 at trans rate) -- 80 activations per lane-row
// made this ~25-35us of chip-wide divide overhead. Replaced with
// __builtin_amdgcn_rcpf (single v_rcp_f32, ~1ulp; absmax tol 0.03 >> 1e-7).
// G (bf16) row layout: [s0=i_i+h_i | s1=i_f+h_f | s2=h_g | s3=i_o+h_o]
// Lane l covers cols {j*512 + l*8 + e : j in 0..1, e in 0..7}.
// ---------------------------------------------------------------------------
__device__ inline float fast_rcp(float x) { return __builtin_amdgcn_rcpf(x); }
__device__ inline float sigmoid_f(float x) {
    return fast_rcp(1.f + __expf(-x));                 // exp + add + rcp
}
// safe fast tanh: exact +/-1 saturation at both ends
__device__ inline float tanh_f(float x) {
    return 1.f - 2.f * fast_rcp(__expf(2.f * x) + 1.f); // exp + add + rcp + fma
}

__device__ inline void wstats(const float* x, float& mu, float& rs)
{
    float s = 0.f, q = 0.f;
#pragma unroll
    for (int e = 0; e < 16; ++e) { s += x[e]; q += x[e] * x[e]; }
#pragma unroll
    for (int o = 1; o < 64; o <<= 1) {
        s += __shfl_xor(s, o);
        q += __shfl_xor(q, o);
    }
    mu = s * (1.f / 1024.f);
    float var = q * (1.f / 1024.f) - mu * mu;
    rs = rsqrtf(var + 1e-5f);
}

// 16 bf16 -> fp32 per thread: two 16B ushort8 loads
#define LOADG16(dst, basep)                                            \
    _Pragma("unroll")                                                  \
    for (int j = 0; j < 2; ++j) {                                      \
        us8 t = *(const us8*)((basep) + j * 512 + cbase);              \
        _Pragma("unroll")                                              \
        for (int e = 0; e < 8; ++e) dst[j * 8 + e] = bf2f(t[e]);       \
    }

// 16 fp32 per thread (params / c_prev): four float4 loads
#define LOADF16(dst, basep)                                            \
    _Pragma("unroll")                                                  \
    for (int j = 0; j < 2; ++j) {                                      \
        float4 a = *(const float4*)((basep) + j * 512 + cbase);        \
        float4 b = *(const float4*)((basep) + j * 512 + cbase + 4);    \
        dst[j * 8 + 0] = a.x; dst[j * 8 + 1] = a.y;                    \
        dst[j * 8 + 2] = a.z; dst[j * 8 + 3] = a.w;                    \
        dst[j * 8 + 4] = b.x; dst[j * 8 + 5] = b.y;                    \
        dst[j * 8 + 6] = b.z; dst[j * 8 + 7] = b.w;                    \
    }

__global__ __launch_bounds__(256) void lstm_ew_kernel(
    const unsigned short* __restrict__ G,
    const float* __restrict__ c_prev,
    const float* __restrict__ p0g, const float* __restrict__ p0b,
    const float* __restrict__ p1g, const float* __restrict__ p1b,
    const float* __restrict__ p2g, const float* __restrict__ p2b,
    const float* __restrict__ p3g, const float* __restrict__ p3b,
    const float* __restrict__ p4g, const float* __restrict__ p4b,
    float* __restrict__ out_h, float* __restrict__ out_c,
    int row_base)
{
    const int lane  = threadIdx.x & 63;
    const int wave  = threadIdx.x >> 6;
    const int r     = blockIdx.x * 4 + wave;
    const int grow  = row_base + r;
    const int cbase = lane * 8;

    const unsigned short* Grow = G + (size_t)r * NDIM;

    float tmp[16], pg[16], pb[16];
    float ig[16], cm[16], og[16];
    float mu, rs;

    // i gate: sigmoid(LN(i_i+h_i; ln_i))
    LOADG16(tmp, Grow);
    wstats(tmp, mu, rs);
    LOADF16(pg, p0g); LOADF16(pb, p0b);
#pragma unroll
    for (int e = 0; e < 16; ++e)
        ig[e] = sigmoid_f((tmp[e] - mu) * rs * pg[e] + pb[e]);

    // f gate: sigmoid(LN(i_f+h_f; ln_h)); cm = f * c_prev
    LOADG16(tmp, Grow + 1024);
    wstats(tmp, mu, rs);
    LOADF16(pg, p1g); LOADF16(pb, p1b);
    LOADF16(cm, c_prev + (size_t)grow * HDIM);
#pragma unroll
    for (int e = 0; e < 16; ++e)
        cm[e] *= sigmoid_f((tmp[e] - mu) * rs * pg[e] + pb[e]);

    // g gate: tanh(LN(i_g + h_g; ln_g))  <- faithful bug: i_g is sigmoided gate
    LOADG16(tmp, Grow + 2048);
#pragma unroll
    for (int e = 0; e < 16; ++e) tmp[e] += ig[e];
    wstats(tmp, mu, rs);
    LOADF16(pg, p2g); LOADF16(pb, p2b);
#pragma unroll
    for (int e = 0; e < 16; ++e)
        cm[e] += ig[e] * tanh_f((tmp[e] - mu) * rs * pg[e] + pb[e]);

    // o gate: sigmoid(LN(i_o+h_o; ln_o))
    LOADG16(tmp, Grow + 3072);
    wstats(tmp, mu, rs);
    LOADF16(pg, p3g); LOADF16(pb, p3b);
#pragma unroll
    for (int e = 0; e < 16; ++e)
        og[e] = sigmoid_f((tmp[e] - mu) * rs * pg[e] + pb[e]);

    // c_new = LN(cm; ln_c); h_new = o * tanh(c_new)
    wstats(cm, mu, rs);
    LOADF16(pg, p4g); LOADF16(pb, p4b);
    float cn[16], hn[16];
#pragma unroll
    for (int e = 0; e < 16; ++e) {
        cn[e] = (cm[e] - mu) * rs * pg[e] + pb[e];
        hn[e] = og[e] * tanh_f(cn[e]);
    }

    float* oh = out_h + (size_t)grow * HDIM;
    float* oc = out_c + (size_t)grow * HDIM;
#pragma unroll
    for (int j = 0; j < 2; ++j) {
        *(float4*)(oh + j * 512 + cbase) =
            make_float4(hn[j*8+0], hn[j*8+1], hn[j*8+2], hn[j*8+3]);
        *(float4*)(oh + j * 512 + cbase + 4) =
            make_float4(hn[j*8+4], hn[j*8+5], hn[j*8+6], hn[j*8+7]);
        *(float4*)(oc + j * 512 + cbase) =
            make_float4(cn[j*8+0], cn[j*8+1], cn[j*8+2], cn[j*8+3]);
        *(float4*)(oc + j * 512 + cbase + 4) =
            make_float4(cn[j*8+4], cn[j*8+5], cn[j*8+6], cn[j*8+7]);
    }
}

extern "C" void kernel_launch(void* const* d_in, const int* in_sizes, int n_in,
                              void* d_out, int out_size, void* d_ws, size_t ws_size,
                              hipStream_t stream)
{
    const float* input  = (const float*)d_in[0];
    const float* h_prev = (const float*)d_in[1];
    const float* c_prev = (const float*)d_in[2];
    const float* w_i    = (const float*)d_in[3];
    const float* w_h    = (const float*)d_in[4];
    const float* lng[10];
    for (int i = 0; i < 10; ++i) lng[i] = (const float*)d_in[5 + i];

    // Workspace: Xb bf16 [8192,2048] | Wb bf16 [4096,2048] | G bf16 [8192,4096]
    // (117.4 MB total; proven to fit.)
    unsigned short* Xb = (unsigned short*)d_ws;
    size_t xb_bytes = (size_t)BATCH * KDIM * 2;
    unsigned short* Wb = (unsigned short*)((char*)d_ws + xb_bytes);
    size_t wb_bytes = (size_t)NDIM * KDIM * 2;
    unsigned short* G = (unsigned short*)((char*)d_ws + xb_bytes + wb_bytes);

    convert_kernel<<<(NDIM * 256 + BATCH * 256) / 256, 256, 0, stream>>>(
        w_i, w_h, input, h_prev, Wb, Xb);

    float* out_h = (float*)d_out;
    float* out_c = out_h + (size_t)BATCH * HDIM;

    // 3 launches total (launch gap ~8-9us each; R8/R9 measured).
    gemm_bt_kernel<<<(BATCH / BM) * (NDIM / BN), 512, 0, stream>>>(
        Xb, Wb, G, BATCH);
    lstm_ew_kernel<<<BATCH / 4, 256, 0, stream>>>(
        G, c_prev, lng[0], lng[1], lng[2], lng[3], lng[4],
        lng[5], lng[6], lng[7], lng[8], lng[9], out_h, out_c, 0);
}